// Round 7
// baseline (210.038 us; speedup 1.0000x reference)
//
#include <hip/hip_runtime.h>
#include <hip/hip_bf16.h>

using u16 = unsigned short;

static constexpr int N  = 2;
static constexpr int C  = 64;
static constexpr int H  = 256;
static constexpr int W  = 256;
static constexpr int Hd = 128;
static constexpr int Wd = 128;
static constexpr int Cm = 64;
static constexpr int KK = 25;
static constexpr int C2 = 256;
static constexpr int OC = 64;
static constexpr int HWP  = H * W;    // 65536
static constexpr int HDWD = Hd * Wd;  // 16384

__device__ __forceinline__ float bflo(unsigned u) { return __uint_as_float(u << 16); }
__device__ __forceinline__ float bfhi(unsigned u) { return __uint_as_float(u & 0xffff0000u); }
__device__ __forceinline__ unsigned pack2(float a, float b) {
    __hip_bfloat16 ha = __float2bfloat16(a), hb = __float2bfloat16(b);
    union { __hip_bfloat16 h; u16 u; } ua{ha}, ub{hb};
    return (unsigned)ua.u | ((unsigned)ub.u << 16);
}

// ---------------- Kernel A: 1x1 down conv -> k1 PIXEL-MAJOR [n][px][cm] -----
// grid(1024): 128-px tile, 4 blocks/CU. thread = 4 px x 8 cm.
__global__ __launch_bounds__(256) void kA_down(const float* __restrict__ x,
                                               const float* __restrict__ w,
                                               const float* __restrict__ b,
                                               u16* __restrict__ k1) {
    __shared__ u16   xt[64][128];    // bf16 x tile [c][px_local]  16 KB
    __shared__ float wt[64][66];     // w transposed [c][cm]       16.9 KB
    const int tid = threadIdx.x;
    const int pg0 = blockIdx.x * 128;
    const int n   = pg0 >> 16;
    const int px0 = pg0 & (HWP - 1);

#pragma unroll
    for (int i = 0; i < 16; ++i) {
        int e  = i * 256 + tid;
        int cm = e >> 6, c = e & 63;
        wt[c][cm] = w[e];
    }
    const float* xb = x + (size_t)n * C * HWP + px0;
#pragma unroll
    for (int i = 0; i < 8; ++i) {
        int flat = i * 256 + tid;              // float4 slot 0..2047
        int row  = flat >> 5;                  // channel
        int col4 = flat & 31;
        float4 v = *(const float4*)(xb + (size_t)row * HWP + col4 * 4);
        uint2 p;
        p.x = pack2(v.x, v.y);
        p.y = pack2(v.z, v.w);
        *(uint2*)&xt[row][col4 * 4] = p;
    }
    __syncthreads();

    const int cg  = tid & 7;                   // cm group of 8
    const int pxg = tid >> 3;                  // 0..31 -> 4 px each
    float acc[8][4];
#pragma unroll
    for (int j = 0; j < 8; ++j) {
        float bj = b[cg * 8 + j];
#pragma unroll
        for (int p = 0; p < 4; ++p) acc[j][p] = bj;
    }
#pragma unroll 8
    for (int c = 0; c < 64; ++c) {
        uint2 xv = *(const uint2*)&xt[c][pxg * 4];
        float xs[4] = {bflo(xv.x), bfhi(xv.x), bflo(xv.y), bfhi(xv.y)};
        float2 w01 = *(const float2*)&wt[c][cg * 8 + 0];
        float2 w23 = *(const float2*)&wt[c][cg * 8 + 2];
        float2 w45 = *(const float2*)&wt[c][cg * 8 + 4];
        float2 w67 = *(const float2*)&wt[c][cg * 8 + 6];
        float wv[8] = {w01.x, w01.y, w23.x, w23.y, w45.x, w45.y, w67.x, w67.y};
#pragma unroll
        for (int j = 0; j < 8; ++j)
#pragma unroll
            for (int p = 0; p < 4; ++p) acc[j][p] = fmaf(wv[j], xs[p], acc[j][p]);
    }
#pragma unroll
    for (int p = 0; p < 4; ++p) {
        uint4 o;
        o.x = pack2(acc[0][p], acc[1][p]);
        o.y = pack2(acc[2][p], acc[3][p]);
        o.z = pack2(acc[4][p], acc[5][p]);
        o.w = pack2(acc[6][p], acc[7][p]);
        *(uint4*)(k1 + ((size_t)pg0 + pxg * 4 + p) * 64 + cg * 8) = o;
    }
}

// ---- Kernel W: repack enc weights  ew[kk][cm][3][3] -> ewt[tap][cm][kk] ----
__global__ __launch_bounds__(256) void kW_repack(const float* __restrict__ ew,
                                                 float* __restrict__ ewt) {
    int i = blockIdx.x * 256 + threadIdx.x;
    if (i < 25 * 64 * 9) {
        int tap = i % 9;
        int r   = i / 9;
        int cm  = r % 64;
        int kk  = r / 64;
        ewt[(tap * 64 + cm) * 25 + kk] = ew[i];
    }
}

// -------- Kernel B: 3x3 s2 enc conv (64->25) + softmax -> ksm fp32 ----------
// grid(512): block = 64 px (one hd row) x 4 cm-quarters. Interior rows take a
// fast path issuing all 18 dwordx4 loads before the FMA stream.
__global__ __launch_bounds__(256) void kB_enc(const u16* __restrict__ k1,
                                              const float* __restrict__ ewt,
                                              const float* __restrict__ eb,
                                              float* __restrict__ ksm) {
    __shared__ float red[4][64][29];
    const int tid  = threadIdx.x;
    const int lane = tid & 63;
    const int quarter = tid >> 6;
    const int pix = blockIdx.x * 64 + lane;
    const int n   = pix >> 14;
    const int hd  = __builtin_amdgcn_readfirstlane((pix >> 7) & 127);  // uniform
    const int wd  = pix & 127;
    const int cm0 = (quarter & 3) * 16;

    float acc[25];
#pragma unroll
    for (int kk = 0; kk < 25; ++kk) acc[kk] = 0.f;

    const u16* kbase = k1 + (size_t)n * HWP * 64;

    if (hd > 0) {      // all three y rows valid (hd<=127 -> y<=255)
        uint4 va[9], vb[9];
#pragma unroll
        for (int t = 0; t < 9; ++t) {
            int dy = t / 3, dx = t - (t / 3) * 3;
            int y  = 2 * hd + dy - 1;
            int xx = 2 * wd + dx - 1;
            int xc = max(xx, 0);
            const u16* kp = kbase + ((size_t)(y * W + xc)) * 64 + cm0;
            va[t] = *(const uint4*)kp;
            vb[t] = *(const uint4*)(kp + 8);
        }
#pragma unroll
        for (int t = 0; t < 9; ++t) {
            float v[16] = {bflo(va[t].x), bfhi(va[t].x), bflo(va[t].y), bfhi(va[t].y),
                           bflo(va[t].z), bfhi(va[t].z), bflo(va[t].w), bfhi(va[t].w),
                           bflo(vb[t].x), bfhi(vb[t].x), bflo(vb[t].y), bfhi(vb[t].y),
                           bflo(vb[t].z), bfhi(vb[t].z), bflo(vb[t].w), bfhi(vb[t].w)};
            if ((t % 3) == 0 && wd == 0) {     // xx=-1 tap: zero (lane-local)
#pragma unroll
                for (int i = 0; i < 16; ++i) v[i] = 0.f;
            }
            const float* wp = ewt + (t * 64 + cm0) * 25;   // uniform s_loads
#pragma unroll
            for (int i = 0; i < 16; ++i)
#pragma unroll
                for (int kk = 0; kk < 25; ++kk)
                    acc[kk] = fmaf(v[i], wp[i * 25 + kk], acc[kk]);
        }
    } else {           // hd==0: dy=0 row out of bounds
        for (int dy = 1; dy < 3; ++dy) {
            int y = dy - 1;
            for (int dx = 0; dx < 3; ++dx) {
                int xx = 2 * wd + dx - 1;
                bool ok = (xx >= 0);
                int xc = max(xx, 0);
                const int tap = dy * 3 + dx;
                const u16* kp = kbase + ((size_t)(y * W + xc)) * 64 + cm0;
                uint4 a = *(const uint4*)kp;
                uint4 bq = *(const uint4*)(kp + 8);
                float v[16] = {bflo(a.x),  bfhi(a.x),  bflo(a.y),  bfhi(a.y),
                               bflo(a.z),  bfhi(a.z),  bflo(a.w),  bfhi(a.w),
                               bflo(bq.x), bfhi(bq.x), bflo(bq.y), bfhi(bq.y),
                               bflo(bq.z), bfhi(bq.z), bflo(bq.w), bfhi(bq.w)};
                if (!ok) {
#pragma unroll
                    for (int i = 0; i < 16; ++i) v[i] = 0.f;
                }
                const float* wp = ewt + (tap * 64 + cm0) * 25;
#pragma unroll
                for (int i = 0; i < 16; ++i)
#pragma unroll
                    for (int kk = 0; kk < 25; ++kk)
                        acc[kk] = fmaf(v[i], wp[i * 25 + kk], acc[kk]);
            }
        }
    }
#pragma unroll
    for (int kk = 0; kk < 25; ++kk) red[quarter][lane][kk] = acc[kk];
    __syncthreads();

    if (tid < 64) {
        float lg[25];
        float m = -1e30f;
#pragma unroll
        for (int kk = 0; kk < 25; ++kk) {
            float s = red[0][tid][kk] + red[1][tid][kk] + red[2][tid][kk]
                    + red[3][tid][kk] + eb[kk];
            lg[kk] = s;
            m = fmaxf(m, s);
        }
        float ssum = 0.f;
#pragma unroll
        for (int kk = 0; kk < 25; ++kk) { lg[kk] = __expf(lg[kk] - m); ssum += lg[kk]; }
        float inv = 1.f / ssum;
        float* ob = ksm + (size_t)n * KK * HDWD + hd * Wd + wd;
#pragma unroll
        for (int kk = 0; kk < 25; ++kk) ob[(size_t)kk * HDWD] = lg[kk] * inv;
    }
}

// ---- Kernel C: weighted reassembly -> out2 (N,256,Hd,Wd) bf16 --------------
// grid(2048), thread = 2 wd outputs, conflict-free flat-slot staging.
__global__ __launch_bounds__(256) void kC_reassemble(const float* __restrict__ x,
                                                     const float* __restrict__ ksm,
                                                     u16* __restrict__ out2) {
    __shared__ float xts[6 * 272];
    const int tid = threadIdx.x;
    const int b   = blockIdx.x;
    const int cchunk = b & 7;
    const int hdt = (b >> 3) & 31;
    const int q   = (b >> 8) & 3;
    const int n   = b >> 10;
    const int hd0 = hdt * 4;
    const int wv   = tid >> 6;
    const int lane = tid & 63;
    const int hd  = hd0 + wv;
    const int wd0 = lane * 2;
    const int w0  = ((wv & 1) << 7) + wd0;
    const int lr0 = wv >> 1;
    const int y0  = q * 64 + (hd0 >> 1) - 2;
    const int c0  = cchunk * 8;

    const float* kb = ksm + (size_t)n * KK * HDWD + hd * Wd + wd0;
    float2 kw[25];
#pragma unroll
    for (int kk = 0; kk < 25; ++kk) kw[kk] = *(const float2*)(kb + (size_t)kk * HDWD);

    const int s0 = tid, s1 = tid + 256;
    const int r0s = s0 / 68, c40 = s0 - r0s * 68;
    const int r1s = s1 / 68, c41 = s1 - r1s * 68;
    const int ya = y0 + r0s, yb = y0 + r1s;
    const bool v0 = (c40 >= 1) & (c40 <= 64) & (ya >= 0) & (ya < H);
    const bool v1 = (s1 < 408) & (c41 >= 1) & (c41 <= 64) & (yb >= 0) & (yb < H);
    const float* xn = x + (size_t)n * C * HWP + (size_t)c0 * HWP;
    const float* g0 = xn + (size_t)ya * W + (c40 - 1) * 4;
    const float* g1 = xn + (size_t)yb * W + (c41 - 1) * 4;

    const float4 z = make_float4(0.f, 0.f, 0.f, 0.f);
    float4 p0 = v0 ? *(const float4*)g0 : z;
    float4 p1 = v1 ? *(const float4*)g1 : z;

    for (int ci = 0; ci < 8; ++ci) {
        __syncthreads();
        *(float4*)&xts[4 * s0] = p0;
        if (s1 < 408) *(float4*)&xts[4 * s1] = p1;
        __syncthreads();

        if (ci < 7) {
            p0 = v0 ? *(const float4*)(g0 + (size_t)(ci + 1) * HWP) : z;
            p1 = v1 ? *(const float4*)(g1 + (size_t)(ci + 1) * HWP) : z;
        }

        float a0 = 0.f, a1 = 0.f;
#pragma unroll
        for (int i = 0; i < 5; ++i) {
            const float* rr = &xts[(lr0 + i) * 272 + w0 + 2];
            float2 r0 = *(const float2*)(rr + 0);
            float2 r1 = *(const float2*)(rr + 2);
            float2 r2 = *(const float2*)(rr + 4);
            float f[6] = {r0.x, r0.y, r1.x, r1.y, r2.x, r2.y};
#pragma unroll
            for (int j = 0; j < 5; ++j) {
                const float2 kv = kw[i * 5 + j];
                a0 = fmaf(f[j + 0], kv.x, a0);
                a1 = fmaf(f[j + 1], kv.y, a1);
            }
        }
        const int c2 = 4 * (c0 + ci) + q;
        u16* op = out2 + ((size_t)(n * C2 + c2) * Hd + hd) * Wd + wd0;
        *(unsigned*)op = pack2(a0, a1);
    }
}

// ---- Kernel D: 1x1 out conv (256 -> 64) -> d_out fp32 ----------------------
// grid(64,16): thread = 2 px x 4 co; 16-deep load batches.
__global__ __launch_bounds__(256) void kD_out(const u16* __restrict__ out2,
                                              const float* __restrict__ ow,
                                              const float* __restrict__ ob,
                                              float* __restrict__ out) {
    const int co0 = blockIdx.y * 4;
    const int pg  = blockIdx.x * 256 + threadIdx.x;   // 0..16383
    const int n   = pg >> 13;
    const int hw  = (pg << 1) & (HDWD - 1);
    const u16* ib = out2 + (size_t)n * C2 * HDWD + hw;

    float acc[4][2];
#pragma unroll
    for (int j = 0; j < 4; ++j) {
        float bj = ob[co0 + j];
        acc[j][0] = bj; acc[j][1] = bj;
    }
    for (int c2 = 0; c2 < 256; c2 += 16) {
        unsigned u[16];
#pragma unroll
        for (int t = 0; t < 16; ++t)
            u[t] = *(const unsigned*)(ib + (size_t)(c2 + t) * HDWD);
#pragma unroll
        for (int t = 0; t < 16; ++t) {
            float x0 = bflo(u[t]), x1 = bfhi(u[t]);
#pragma unroll
            for (int j = 0; j < 4; ++j) {
                float wv = ow[(co0 + j) * 256 + c2 + t];   // uniform -> s_load
                acc[j][0] = fmaf(wv, x0, acc[j][0]);
                acc[j][1] = fmaf(wv, x1, acc[j][1]);
            }
        }
    }
#pragma unroll
    for (int j = 0; j < 4; ++j) {
        float* op = out + (size_t)(n * OC + co0 + j) * HDWD + hw;
        *(float2*)op = make_float2(acc[j][0], acc[j][1]);
    }
}

extern "C" void kernel_launch(void* const* d_in, const int* in_sizes, int n_in,
                              void* d_out, int out_size, void* d_ws, size_t ws_size,
                              hipStream_t stream) {
    const float* x  = (const float*)d_in[0];
    const float* dw = (const float*)d_in[1];
    const float* db = (const float*)d_in[2];
    const float* ew = (const float*)d_in[3];
    const float* eb = (const float*)d_in[4];
    const float* ow = (const float*)d_in[5];
    const float* ob = (const float*)d_in[6];
    float* out = (float*)d_out;

    char* ws = (char*)d_ws;
    u16*   k1   = (u16*)ws;                               // [n][px][cm] 16.8 MB
    float* ksm  = (float*)(ws + 16777216);                // 3.3 MB
    u16*   out2 = (u16*)(ws + 16777216 + 3276800);        // 16.8 MB
    float* ewt  = (float*)out2;   // kW writes, kB reads, kC clobbers after

    kW_repack<<<dim3(57), dim3(256), 0, stream>>>(ew, ewt);
    kA_down<<<dim3(1024), dim3(256), 0, stream>>>(x, dw, db, k1);
    kB_enc<<<dim3(512), dim3(256), 0, stream>>>(k1, ewt, eb, ksm);
    kC_reassemble<<<dim3(2048), dim3(256), 0, stream>>>(x, ksm, out2);
    kD_out<<<dim3(64, 16), dim3(256), 0, stream>>>(out2, ow, ob, out);
}